// Round 14
// baseline (130.575 us; speedup 1.0000x reference)
//
#include <hip/hip_runtime.h>
#include <math.h>

// Problem constants
#define NIMG 512          // B*C = 64*8
#define HH   256          // H
#define MM   32           // M (kept modes per axis)
#define EPSF 1e-8f
#define PAD2 18           // T2 row stride in float2 (144B rows)

// d_out float offsets (outputs concatenated flat in reference return order)
#define O0 0u             // modal_energies        [512][32][32]
#define O1 524288u        // modal_uncertainties   [512][32][32]
#define O2 1048576u       // energy_fractions      [512][32][32]
#define O3 1572864u       // weighted_importance   [512][32][32]
#define O4 2097152u       // uncertainty_spectrum  [32][32]
#define O5 2098176u       // energy_spectrum       [32][32]
#define O6 2099200u       // modal_errors          [512][32][32]
#define O7 2623488u       // calibration_scores    [32][32]

// d_ws float offsets
#define TW_OFF  0                            // 256 x (cos,sin) = 512 floats
#define PM_OFF  512                          // pred modes [512][32][32][2]
#define GM_OFF  (512 + NIMG*MM*MM*2)         // gt modes
#define TOT_OFF (512 + 2*NIMG*MM*MM*2)       // per-image HALF energies [512][2]

// ---------------------------------------------------------------------------
// Twiddle table in GLOBAL memory: tw[i] = (cos, sin)(2*pi*i/256).
// All dft twiddle indices are wave-uniform -> compiler emits s_load_dwordx2
// (scalar pipe): no vector-issue cost, no LDS ds_read latency chain (r13's
// ~10 ds_reads/body were a per-body lgkmcnt chain). 2KB, L2-resident.
__global__ void init_tw_kernel(float* __restrict__ tw) {
  int t = threadIdx.x;  // 256 threads
  double th = (2.0 * M_PI / 256.0) * (double)t;
  tw[2*t]   = (float)cos(th);
  tw[2*t+1] = (float)sin(th);
}

// ---------------------------------------------------------------------------
// Truncated 2D DFT, k1-PARITY-SPLIT (r13 structure, proven): TWO blocks per
// (image, tensor); half=0 computes even k1 (s[n1]=x[n1]+x[n1+128]), half=1
// odd k1 (d[n1]=x[n1]-x[n1+128], W256^n1 pre-twist folded into odd-index
// 8-pt kernel). 16 complex accs = 32 floats/thread.
// waves_per_eu(4,4): LDS 36.9KB allows exactly 4 blocks/CU = 4 waves/EU;
// 128-VGPR budget fits the ~95-reg demand -> no AGPR shuttle, 50% occupancy.
// Stage 2: single pass, radix-4 fold over n2, residue k2%4 wave-uniform;
// global k1 = 2*k1l + half. XCD-chunked swizzle pairs halves on one XCD.
__global__ __attribute__((amdgpu_waves_per_eu(4, 4))) __launch_bounds__(256)
void dft_kernel(
    const float* __restrict__ pred, const float* __restrict__ gt,
    const float* __restrict__ tw,
    float* __restrict__ Pm, float* __restrict__ Gm,
    float* __restrict__ totp, float* __restrict__ out_energy)
{
  __shared__ __align__(16) float2 T2[256 * PAD2];   // 36864 B
  __shared__ float red[4];

  const int t    = threadIdx.x;
  const int w    = t >> 6;           // wave 0..3
  const int l    = t & 63;
  // XCD-chunked swizzle (2048 = 8 XCD x 256): consecutive logical ids (the
  // img half-pair) land on the same XCD -> 2nd image read is an L2 hit.
  const int p    = blockIdx.x;
  const int lbid = (p & 7) * 256 + (p >> 3);
  const int half = lbid & 1;
  const int img  = (lbid >> 1) & (NIMG - 1);
  const int isGt = lbid >> 10;
  const float* __restrict__ x =
      (isGt ? gt : pred) + (size_t)img * (HH * HH);
  const float2* __restrict__ twg = (const float2*)tw;

  // ---- stage 1 ----
  float accR[16], accI[16];
#pragma unroll
  for (int k = 0; k < 16; ++k) { accR[k] = 0.f; accI[k] = 0.f; }

  // ACC2: X[r] += Y ; X[8+r] += (tm.x, -tm.y) (x) Y   (tm = W16^a)
#define ACC2(r, Yr, Yi)                                                   \
    accR[(r)] += (Yr);  accI[(r)] += (Yi);                                \
    accR[8+(r)] = fmaf(tm.x,(Yr), fmaf( tm.y,(Yi), accR[8+(r)]));         \
    accI[8+(r)] = fmaf(tm.x,(Yi), fmaf(-(tm.y),(Yr), accI[8+(r)]));

#define CPLX_E(r, aa, Zr, Zi)                                             \
    { float2 tt = twg[(2*(r)*(aa)) & 255];                                \
      float Yr = fmaf(tt.x,(Zr),  tt.y*(Zi));                             \
      float Yi = fmaf(tt.x,(Zi), -(tt.y*(Zr)));                           \
      ACC2(r, Yr, Yi) }

#define CPLX_O(r, j, aa, Dr, Di)                                          \
    { float2 tt = twg[((j)*(aa)) & 255];                                  \
      float Yr = fmaf(tt.x,(Dr),  tt.y*(Di));                             \
      float Yi = fmaf(tt.x,(Di), -(tt.y*(Dr)));                           \
      ACC2(r, Yr, Yi) }

#define LOADV(V, aa)                                                      \
    V[0]  = x[((aa)      )*256 + t]; V[1]  = x[((aa) +  16)*256 + t];     \
    V[2]  = x[((aa) +  32)*256 + t]; V[3]  = x[((aa) +  48)*256 + t];     \
    V[4]  = x[((aa) +  64)*256 + t]; V[5]  = x[((aa) +  80)*256 + t];     \
    V[6]  = x[((aa) +  96)*256 + t]; V[7]  = x[((aa) + 112)*256 + t];     \
    V[8]  = x[((aa) + 128)*256 + t]; V[9]  = x[((aa) + 144)*256 + t];     \
    V[10] = x[((aa) + 160)*256 + t]; V[11] = x[((aa) + 176)*256 + t];     \
    V[12] = x[((aa) + 192)*256 + t]; V[13] = x[((aa) + 208)*256 + t];     \
    V[14] = x[((aa) + 224)*256 + t]; V[15] = x[((aa) + 240)*256 + t];

  // EVEN half: s_b = V[b]+V[b+8]; standard real 8-pt DFT; Y_r = W128^{ar} Z_r
#define BODY_E(V, aa)                                                     \
  {                                                                       \
    float s0=V[0]+V[8],  s1=V[1]+V[9],  s2=V[2]+V[10], s3=V[3]+V[11];     \
    float s4=V[4]+V[12], s5=V[5]+V[13], s6=V[6]+V[14], s7=V[7]+V[15];     \
    float w0=s0+s4, w1=s1+s5, w2=s2+s6, w3=s3+s7;                         \
    float e0=s0-s4, e1=s1-s5, e2=s2-s6, e3=s3-s7;                         \
    float A0=w0+w2, A1=w0-w2, A2=w1+w3, A3=w1-w3;                         \
    float Z0=A0+A2, Z4=A0-A2;                                             \
    float Z2r=A1, Z2i=-A3;                                                \
    float pp=0.70710678f*(e1-e3), qq2=0.70710678f*(e1+e3);                \
    float Z1r=e0+pp, Z1i=-(e2+qq2);                                       \
    float Z3r=e0-pp, Z3i=e2-qq2;                                          \
    float2 tm = twg[(16*(aa)) & 255];                                     \
    accR[0] += Z0;                                                        \
    accR[8] = fmaf(tm.x,Z0,accR[8]); accI[8] = fmaf(-tm.y,Z0,accI[8]);    \
    { float2 tt = twg[(8*(aa)) & 255];                                    \
      float Yr = tt.x*Z4, Yi = -(tt.y*Z4);                                \
      ACC2(4, Yr, Yi) }                                                   \
    CPLX_E(1,(aa),Z1r, Z1i) CPLX_E(2,(aa),Z2r, Z2i) CPLX_E(3,(aa),Z3r, Z3i) \
    CPLX_E(5,(aa),Z3r,-Z3i) CPLX_E(6,(aa),Z2r,-Z2i) CPLX_E(7,(aa),Z1r,-Z1i) \
  }

  // ODD half: d_b = V[b]-V[b+8]; odd-index 8-pt kernel (freq (2r+1)/16);
  // D_{7-r} = conj(D_r); Y_r = W256^{a(2r+1)} D_r
#define BODY_O(V, aa)                                                     \
  {                                                                       \
    float d0=V[0]-V[8],  d1=V[1]-V[9],  d2=V[2]-V[10], d3=V[3]-V[11];     \
    float d4=V[4]-V[12], d5=V[5]-V[13], d6=V[6]-V[14], d7=V[7]-V[15];     \
    float p1=d1-d7, p2=d2-d6, p3=d3-d5;                                   \
    float q1=d1+d7, q2=d2+d6, q3=d3+d5;                                   \
    float R0=d0+fmaf(0.92387953f,p1,fmaf( 0.70710678f,p2, 0.38268343f*p3)); \
    float I0=-d4-fmaf(0.38268343f,q1,fmaf( 0.70710678f,q2, 0.92387953f*q3)); \
    float R1=d0+fmaf(0.38268343f,p1,fmaf(-0.70710678f,p2,-0.92387953f*p3)); \
    float I1= d4-fmaf(0.92387953f,q1,fmaf( 0.70710678f,q2,-0.38268343f*q3)); \
    float R2=d0+fmaf(-0.38268343f,p1,fmaf(-0.70710678f,p2, 0.92387953f*p3)); \
    float I2=-d4-fmaf( 0.92387953f,q1,fmaf(-0.70710678f,q2,-0.38268343f*q3)); \
    float R3=d0+fmaf(-0.92387953f,p1,fmaf( 0.70710678f,p2,-0.38268343f*p3)); \
    float I3= d4-fmaf( 0.38268343f,q1,fmaf(-0.70710678f,q2, 0.92387953f*q3)); \
    float2 tm = twg[(16*(aa)) & 255];                                     \
    CPLX_O(0, 1,(aa),R0, I0) CPLX_O(1, 3,(aa),R1, I1)                     \
    CPLX_O(2, 5,(aa),R2, I2) CPLX_O(3, 7,(aa),R3, I3)                     \
    CPLX_O(4, 9,(aa),R3,-I3) CPLX_O(5,11,(aa),R2,-I2)                     \
    CPLX_O(6,13,(aa),R1,-I1) CPLX_O(7,15,(aa),R0,-I0)                     \
  }

  {
    float vA[16], vB[16];
    if (half == 0) {
      LOADV(vA, 0)
      LOADV(vB, 1)
#pragma unroll 1
      for (int a = 0; a < 16; a += 2) {
        BODY_E(vA, a)
        if (a < 14) { LOADV(vA, a + 2) }
        BODY_E(vB, a + 1)
        if (a < 14) { LOADV(vB, a + 3) }
      }
    } else {
      LOADV(vA, 0)
      LOADV(vB, 1)
#pragma unroll 1
      for (int a = 0; a < 16; a += 2) {
        BODY_O(vA, a)
        if (a < 14) { LOADV(vA, a + 2) }
        BODY_O(vB, a + 1)
        if (a < 14) { LOADV(vB, a + 3) }
      }
    }
  }
#undef BODY_E
#undef BODY_O
#undef LOADV
#undef CPLX_E
#undef CPLX_O
#undef ACC2

  // ---- stage 2: single pass, radix-4 fold over n2 ----
  float* __restrict__ Mo = (isGt ? Gm : Pm) + (size_t)img * (MM * MM * 2);
  const int wv  = w;             // residue k2 % 4 (wave-uniform)
  const int k1l = l >> 2;        // local k1 row 0..15
  const int qq  = l & 3;
  const int k2A = 4 * qq + wv;
  const int k2B = k2A + 16;
  float2 tA = twg[k2A]; const float cA = tA.x, sA = -tA.y;
  float2 tB = twg[k2B]; const float cB = tB.x, sB = -tB.y;
  const float se = (wv & 1) ? -1.f : 1.f;     // fold sign for T_c/T_3
  const float cc = (wv < 2) ? 1.f : -1.f;     // second-term sign
  const bool  ev = (wv & 1) == 0;

  // flush 16 accs -> T2[t][0..15]
  {
    float4* rowp = (float4*)&T2[t * PAD2];
    rowp[0] = make_float4(accR[ 0],accI[ 0],accR[ 1],accI[ 1]);
    rowp[1] = make_float4(accR[ 2],accI[ 2],accR[ 3],accI[ 3]);
    rowp[2] = make_float4(accR[ 4],accI[ 4],accR[ 5],accI[ 5]);
    rowp[3] = make_float4(accR[ 6],accI[ 6],accR[ 7],accI[ 7]);
    rowp[4] = make_float4(accR[ 8],accI[ 8],accR[ 9],accI[ 9]);
    rowp[5] = make_float4(accR[10],accI[10],accR[11],accI[11]);
    rowp[6] = make_float4(accR[12],accI[12],accR[13],accI[13]);
    rowp[7] = make_float4(accR[14],accI[14],accR[15],accI[15]);
  }
  __syncthreads();

  float eacc = 0.f;
  {
    float wAr = 1.f, wAi = 0.f, wBr = 1.f, wBi = 0.f;
    float XAr = 0.f, XAi = 0.f, XBr = 0.f, XBi = 0.f;
#pragma unroll 4
    for (int n2 = 0; n2 < 64; ++n2) {
      float2 T0 = T2[(n2      ) * PAD2 + k1l];
      float2 T1 = T2[(n2 +  64) * PAD2 + k1l];
      float2 Tc = T2[(n2 + 128) * PAD2 + k1l];
      float2 T3 = T2[(n2 + 192) * PAD2 + k1l];
      float sr = fmaf(se, Tc.x, T0.x), si = fmaf(se, Tc.y, T0.y);
      float tr = fmaf(se, T3.x, T1.x), ti = fmaf(se, T3.y, T1.y);
      float ur = ev ? tr : ti;
      float ui = ev ? ti : -tr;
      float yr = fmaf(cc, ur, sr), yi = fmaf(cc, ui, si);
      XAr = fmaf(wAr, yr, fmaf(-wAi, yi, XAr));
      XAi = fmaf(wAr, yi, fmaf( wAi, yr, XAi));
      XBr = fmaf(wBr, yr, fmaf(-wBi, yi, XBr));
      XBi = fmaf(wBr, yi, fmaf( wBi, yr, XBi));
      float nAr = fmaf(wAr, cA, -(wAi * sA));
      float nAi = fmaf(wAr, sA,  (wAi * cA));
      float nBr = fmaf(wBr, cB, -(wBi * sB));
      float nBi = fmaf(wBr, sB,  (wBi * cB));
      wAr = nAr; wAi = nAi; wBr = nBr; wBi = nBi;
    }
    const int k1g = 2 * k1l + half;          // parity-split global k1
    const int mA  = k1g * MM + k2A;
    const int mB  = k1g * MM + k2B;
    ((float2*)Mo)[mA] = make_float2(XAr, XAi);
    ((float2*)Mo)[mB] = make_float2(XBr, XBi);
    if (!isGt) {
      float eA = fmaf(XAr, XAr, XAi * XAi);
      float eB = fmaf(XBr, XBr, XBi * XBi);
      out_energy[(size_t)img * (MM * MM) + mA] = eA;
      out_energy[(size_t)img * (MM * MM) + mB] = eB;
      eacc += eA + eB;
    }
  }

  if (!isGt) {   // block-uniform branch: per-half partial energy
#pragma unroll
    for (int off = 32; off >= 1; off >>= 1) eacc += __shfl_down(eacc, off);
    if (l == 0) red[w] = eacc;
    __syncthreads();
    if (t == 0) totp[2 * img + half] = (red[0] + red[1]) + (red[2] + red[3]);
  }
}

// ---------------------------------------------------------------------------
// Per-mode MLP + elementwise outputs. One thread per (img, mode).
__global__ __launch_bounds__(256) void mlp_kernel(
    const float* __restrict__ Pm, const float* __restrict__ Gm,
    const float* __restrict__ totp,
    const float* __restrict__ W1, const float* __restrict__ b1,
    const float* __restrict__ W2, const float* __restrict__ b2,
    const float* __restrict__ W3, const float* __restrict__ b3,
    float* __restrict__ out)
{
  int gid = blockIdx.x * 256 + threadIdx.x;   // 0 .. 524287
  int img = gid >> 10;

  float2 pm = *(const float2*)&Pm[2 * (size_t)gid];
  float2 gm = *(const float2*)&Gm[2 * (size_t)gid];

  float er = pm.x - gm.x, ei = pm.y - gm.y;
  float merr   = fmaf(er, er, ei * ei);
  float energy = fmaf(pm.x, pm.x, pm.y * pm.y);
  float tot    = totp[2 * img] + totp[2 * img + 1];
  float frac   = energy / (tot + EPSF);

  float h1[64];
#pragma unroll
  for (int j = 0; j < 64; ++j)
    h1[j] = fmaxf(fmaf(pm.x, W1[j], fmaf(pm.y, W1[64 + j], b1[j])), 0.f);

  float h2[32];
#pragma unroll
  for (int k = 0; k < 32; ++k) h2[k] = b2[k];
#pragma unroll
  for (int j = 0; j < 64; ++j) {
#pragma unroll
    for (int k = 0; k < 32; ++k)
      h2[k] = fmaf(h1[j], W2[j * 32 + k], h2[k]);
  }
  float z = b3[0];
#pragma unroll
  for (int k = 0; k < 32; ++k) z = fmaf(fmaxf(h2[k], 0.f), W3[k], z);

  float u = fmaxf(z, 0.f) + log1pf(expf(-fabsf(z)));

  out[O0 + gid] = energy;
  out[O1 + gid] = u;
  out[O2 + gid] = frac;
  out[O3 + gid] = frac * u;
  out[O6 + gid] = merr;
}

// ---------------------------------------------------------------------------
// Per-mode reductions over the 512-image axis: spectra + Pearson correlation.
__global__ __launch_bounds__(64) void corr_kernel(float* __restrict__ out)
{
  int mode = blockIdx.x;     // 0..1023
  int lane = threadIdx.x;    // 0..63

  double su = 0.0, se = 0.0, sen = 0.0, suu = 0.0, see = 0.0, sue = 0.0;
  for (int i = lane; i < NIMG; i += 64) {
    float u  = out[O1 + (size_t)i * 1024 + mode];
    float e  = out[O6 + (size_t)i * 1024 + mode];
    float en = out[O0 + (size_t)i * 1024 + mode];
    su  += (double)u;  se  += (double)e;  sen += (double)en;
    suu += (double)u * (double)u;
    see += (double)e * (double)e;
    sue += (double)u * (double)e;
  }
#pragma unroll
  for (int off = 32; off >= 1; off >>= 1) {
    su  += __shfl_down(su,  off);
    se  += __shfl_down(se,  off);
    sen += __shfl_down(sen, off);
    suu += __shfl_down(suu, off);
    see += __shfl_down(see, off);
    sue += __shfl_down(sue, off);
  }
  if (lane == 0) {
    const double N = (double)NIMG;
    double num = sue - su * se / N;
    double du  = suu - su * su / N;
    double de  = see - se * se / N;
    double den = sqrt(du * de);
    out[O4 + mode] = (float)(su / N);
    out[O5 + mode] = (float)(sen / N);
    out[O7 + mode] = (float)(num / (den + 1e-8));
  }
}

// ---------------------------------------------------------------------------
extern "C" void kernel_launch(void* const* d_in, const int* in_sizes, int n_in,
                              void* d_out, int out_size, void* d_ws, size_t ws_size,
                              hipStream_t stream)
{
  const float* pred = (const float*)d_in[0];
  const float* gt   = (const float*)d_in[2];
  const float* W1   = (const float*)d_in[3];
  const float* b1   = (const float*)d_in[4];
  const float* W2   = (const float*)d_in[5];
  const float* b2   = (const float*)d_in[6];
  const float* W3   = (const float*)d_in[7];
  const float* b3   = (const float*)d_in[8];

  float* out  = (float*)d_out;
  float* ws   = (float*)d_ws;
  float* tw   = ws + TW_OFF;
  float* Pm   = ws + PM_OFF;
  float* Gm   = ws + GM_OFF;
  float* totp = ws + TOT_OFF;

  hipLaunchKernelGGL(init_tw_kernel, dim3(1), dim3(256), 0, stream, tw);
  hipLaunchKernelGGL(dft_kernel, dim3(2048), dim3(256), 0, stream,
                     pred, gt, tw, Pm, Gm, totp, out + O0);
  hipLaunchKernelGGL(mlp_kernel, dim3(2048), dim3(256), 0, stream,
                     Pm, Gm, totp, W1, b1, W2, b2, W3, b3, out);
  hipLaunchKernelGGL(corr_kernel, dim3(1024), dim3(64), 0, stream, out);
}

// Round 15
// 123.311 us; speedup vs baseline: 1.0589x; 1.0589x over previous
//
#include <hip/hip_runtime.h>
#include <math.h>

// Problem constants
#define NIMG 512          // B*C = 64*8
#define HH   256          // H
#define MM   32           // M (kept modes per axis)
#define EPSF 1e-8f
#define PAD2 18           // T2 row stride in float2 (144B rows)

// d_out float offsets (outputs concatenated flat in reference return order)
#define O0 0u             // modal_energies        [512][32][32]
#define O1 524288u        // modal_uncertainties   [512][32][32]
#define O2 1048576u       // energy_fractions      [512][32][32]
#define O3 1572864u       // weighted_importance   [512][32][32]
#define O4 2097152u       // uncertainty_spectrum  [32][32]
#define O5 2098176u       // energy_spectrum       [32][32]
#define O6 2099200u       // modal_errors          [512][32][32]
#define O7 2623488u       // calibration_scores    [32][32]

// d_ws float offsets
#define PM_OFF  512                          // pred modes [512][32][32][2]
#define GM_OFF  (512 + NIMG*MM*MM*2)         // gt modes
#define TOT_OFF (512 + 2*NIMG*MM*MM*2)       // per-image HALF energies [512][2]

// ---------------------------------------------------------------------------
// Truncated 2D DFT, k1-PARITY-SPLIT (r13 structure, proven): TWO blocks per
// (image, tensor); half=0 computes even k1 (s[n1]=x[n1]+x[n1+128]), half=1
// odd k1 (d[n1]=x[n1]-x[n1+128], W256^n1 pre-twist folded into odd-index
// 8-pt kernel). 16 complex accs = 32 floats/thread.
// r15 change vs r13 (one design variable): SINGLE load buffer per body (no
// ping-pong; -16 regs -> ~78-reg demand fits the 128 cap with slack, no
// spill/AGPR pressure - r14's spill lesson) + waves_per_eu(4,4) to pin the
// allocator at 4 waves/EU (LDS 39.4KB => exactly 4 blocks/CU). Latency
// hiding by TLP: 4 waves round-robin over [16-load batch | ~200cy compute].
// Stage 2: single pass, radix-4 fold over n2, residue k2%4 wave-uniform;
// global k1 = 2*k1l + half. XCD-chunked swizzle pairs halves on one XCD
// -> second image read is an L2 hit.
__global__ __attribute__((amdgpu_waves_per_eu(4, 4))) __launch_bounds__(256)
void dft_kernel(
    const float* __restrict__ pred, const float* __restrict__ gt,
    float* __restrict__ Pm, float* __restrict__ Gm,
    float* __restrict__ totp, float* __restrict__ out_energy)
{
  __shared__ __align__(16) float2 T2[256 * PAD2];   // 36864 B
  __shared__ float2 tws[256];                       // 2 KB twiddle table
  __shared__ float red[4];

  const int t    = threadIdx.x;
  const int w    = t >> 6;           // wave 0..3
  const int l    = t & 63;
  // XCD-chunked swizzle (2048 = 8 XCD x 256): consecutive logical ids (the
  // img half-pair) land on the same XCD -> 2nd image read is an L2 hit.
  const int p    = blockIdx.x;
  const int lbid = (p & 7) * 256 + (p >> 3);
  const int half = lbid & 1;
  const int img  = (lbid >> 1) & (NIMG - 1);
  const int isGt = lbid >> 10;
  const float* __restrict__ x =
      (isGt ? gt : pred) + (size_t)img * (HH * HH);

  // twiddle table: tws[i] = (cos, sin)(2*pi*i/256)
  {
    float sn, cs;
    __sincosf((float)(2.0 * M_PI / 256.0) * (float)t, &sn, &cs);
    tws[t] = make_float2(cs, sn);
  }
  __syncthreads();

  // ---- stage 1 ----
  float accR[16], accI[16];
#pragma unroll
  for (int k = 0; k < 16; ++k) { accR[k] = 0.f; accI[k] = 0.f; }

  // ACC2: X[r] += Y ; X[8+r] += (tm.x, -tm.y) (x) Y   (tm = W16^a)
#define ACC2(r, Yr, Yi)                                                   \
    accR[(r)] += (Yr);  accI[(r)] += (Yi);                                \
    accR[8+(r)] = fmaf(tm.x,(Yr), fmaf( tm.y,(Yi), accR[8+(r)]));         \
    accI[8+(r)] = fmaf(tm.x,(Yi), fmaf(-(tm.y),(Yr), accI[8+(r)]));

#define CPLX_E(r, aa, Zr, Zi)                                             \
    { float2 tt = tws[(2*(r)*(aa)) & 255];                                \
      float Yr = fmaf(tt.x,(Zr),  tt.y*(Zi));                             \
      float Yi = fmaf(tt.x,(Zi), -(tt.y*(Zr)));                           \
      ACC2(r, Yr, Yi) }

#define CPLX_O(r, j, aa, Dr, Di)                                          \
    { float2 tt = tws[((j)*(aa)) & 255];                                  \
      float Yr = fmaf(tt.x,(Dr),  tt.y*(Di));                             \
      float Yi = fmaf(tt.x,(Di), -(tt.y*(Dr)));                           \
      ACC2(r, Yr, Yi) }

#define LOADV(V, aa)                                                      \
    V[0]  = x[((aa)      )*256 + t]; V[1]  = x[((aa) +  16)*256 + t];     \
    V[2]  = x[((aa) +  32)*256 + t]; V[3]  = x[((aa) +  48)*256 + t];     \
    V[4]  = x[((aa) +  64)*256 + t]; V[5]  = x[((aa) +  80)*256 + t];     \
    V[6]  = x[((aa) +  96)*256 + t]; V[7]  = x[((aa) + 112)*256 + t];     \
    V[8]  = x[((aa) + 128)*256 + t]; V[9]  = x[((aa) + 144)*256 + t];     \
    V[10] = x[((aa) + 160)*256 + t]; V[11] = x[((aa) + 176)*256 + t];     \
    V[12] = x[((aa) + 192)*256 + t]; V[13] = x[((aa) + 208)*256 + t];     \
    V[14] = x[((aa) + 224)*256 + t]; V[15] = x[((aa) + 240)*256 + t];

  // EVEN half: s_b = V[b]+V[b+8]; standard real 8-pt DFT; Y_r = W128^{ar} Z_r
#define BODY_E(V, aa)                                                     \
  {                                                                       \
    float s0=V[0]+V[8],  s1=V[1]+V[9],  s2=V[2]+V[10], s3=V[3]+V[11];     \
    float s4=V[4]+V[12], s5=V[5]+V[13], s6=V[6]+V[14], s7=V[7]+V[15];     \
    float w0=s0+s4, w1=s1+s5, w2=s2+s6, w3=s3+s7;                         \
    float e0=s0-s4, e1=s1-s5, e2=s2-s6, e3=s3-s7;                         \
    float A0=w0+w2, A1=w0-w2, A2=w1+w3, A3=w1-w3;                         \
    float Z0=A0+A2, Z4=A0-A2;                                             \
    float Z2r=A1, Z2i=-A3;                                                \
    float pp=0.70710678f*(e1-e3), qq2=0.70710678f*(e1+e3);                \
    float Z1r=e0+pp, Z1i=-(e2+qq2);                                       \
    float Z3r=e0-pp, Z3i=e2-qq2;                                          \
    float2 tm = tws[(16*(aa)) & 255];                                     \
    accR[0] += Z0;                                                        \
    accR[8] = fmaf(tm.x,Z0,accR[8]); accI[8] = fmaf(-tm.y,Z0,accI[8]);    \
    { float2 tt = tws[(8*(aa)) & 255];                                    \
      float Yr = tt.x*Z4, Yi = -(tt.y*Z4);                                \
      ACC2(4, Yr, Yi) }                                                   \
    CPLX_E(1,(aa),Z1r, Z1i) CPLX_E(2,(aa),Z2r, Z2i) CPLX_E(3,(aa),Z3r, Z3i) \
    CPLX_E(5,(aa),Z3r,-Z3i) CPLX_E(6,(aa),Z2r,-Z2i) CPLX_E(7,(aa),Z1r,-Z1i) \
  }

  // ODD half: d_b = V[b]-V[b+8]; odd-index 8-pt kernel (freq (2r+1)/16);
  // D_{7-r} = conj(D_r); Y_r = W256^{a(2r+1)} D_r
#define BODY_O(V, aa)                                                     \
  {                                                                       \
    float d0=V[0]-V[8],  d1=V[1]-V[9],  d2=V[2]-V[10], d3=V[3]-V[11];     \
    float d4=V[4]-V[12], d5=V[5]-V[13], d6=V[6]-V[14], d7=V[7]-V[15];     \
    float p1=d1-d7, p2=d2-d6, p3=d3-d5;                                   \
    float q1=d1+d7, q2=d2+d6, q3=d3+d5;                                   \
    float R0=d0+fmaf(0.92387953f,p1,fmaf( 0.70710678f,p2, 0.38268343f*p3)); \
    float I0=-d4-fmaf(0.38268343f,q1,fmaf( 0.70710678f,q2, 0.92387953f*q3)); \
    float R1=d0+fmaf(0.38268343f,p1,fmaf(-0.70710678f,p2,-0.92387953f*p3)); \
    float I1= d4-fmaf(0.92387953f,q1,fmaf( 0.70710678f,q2,-0.38268343f*q3)); \
    float R2=d0+fmaf(-0.38268343f,p1,fmaf(-0.70710678f,p2, 0.92387953f*p3)); \
    float I2=-d4-fmaf( 0.92387953f,q1,fmaf(-0.70710678f,q2,-0.38268343f*q3)); \
    float R3=d0+fmaf(-0.92387953f,p1,fmaf( 0.70710678f,p2,-0.38268343f*p3)); \
    float I3= d4-fmaf( 0.38268343f,q1,fmaf(-0.70710678f,q2, 0.92387953f*q3)); \
    float2 tm = tws[(16*(aa)) & 255];                                     \
    CPLX_O(0, 1,(aa),R0, I0) CPLX_O(1, 3,(aa),R1, I1)                     \
    CPLX_O(2, 5,(aa),R2, I2) CPLX_O(3, 7,(aa),R3, I3)                     \
    CPLX_O(4, 9,(aa),R3,-I3) CPLX_O(5,11,(aa),R2,-I2)                     \
    CPLX_O(6,13,(aa),R1,-I1) CPLX_O(7,15,(aa),R0,-I0)                     \
  }

  {
    float vA[16];
    if (half == 0) {
#pragma unroll 1
      for (int a = 0; a < 16; ++a) {
        LOADV(vA, a)
        BODY_E(vA, a)
      }
    } else {
#pragma unroll 1
      for (int a = 0; a < 16; ++a) {
        LOADV(vA, a)
        BODY_O(vA, a)
      }
    }
  }
#undef BODY_E
#undef BODY_O
#undef LOADV
#undef CPLX_E
#undef CPLX_O
#undef ACC2

  // ---- stage 2: single pass, radix-4 fold over n2 ----
  float* __restrict__ Mo = (isGt ? Gm : Pm) + (size_t)img * (MM * MM * 2);
  const int wv  = w;             // residue k2 % 4 (wave-uniform)
  const int k1l = l >> 2;        // local k1 row 0..15
  const int qq  = l & 3;
  const int k2A = 4 * qq + wv;
  const int k2B = k2A + 16;
  float2 tA = tws[k2A]; const float cA = tA.x, sA = -tA.y;
  float2 tB = tws[k2B]; const float cB = tB.x, sB = -tB.y;
  const float se = (wv & 1) ? -1.f : 1.f;     // fold sign for T_c/T_3
  const float cc = (wv < 2) ? 1.f : -1.f;     // second-term sign
  const bool  ev = (wv & 1) == 0;

  // flush 16 accs -> T2[t][0..15]
  {
    float4* rowp = (float4*)&T2[t * PAD2];
    rowp[0] = make_float4(accR[ 0],accI[ 0],accR[ 1],accI[ 1]);
    rowp[1] = make_float4(accR[ 2],accI[ 2],accR[ 3],accI[ 3]);
    rowp[2] = make_float4(accR[ 4],accI[ 4],accR[ 5],accI[ 5]);
    rowp[3] = make_float4(accR[ 6],accI[ 6],accR[ 7],accI[ 7]);
    rowp[4] = make_float4(accR[ 8],accI[ 8],accR[ 9],accI[ 9]);
    rowp[5] = make_float4(accR[10],accI[10],accR[11],accI[11]);
    rowp[6] = make_float4(accR[12],accI[12],accR[13],accI[13]);
    rowp[7] = make_float4(accR[14],accI[14],accR[15],accI[15]);
  }
  __syncthreads();

  float eacc = 0.f;
  {
    float wAr = 1.f, wAi = 0.f, wBr = 1.f, wBi = 0.f;
    float XAr = 0.f, XAi = 0.f, XBr = 0.f, XBi = 0.f;
#pragma unroll 4
    for (int n2 = 0; n2 < 64; ++n2) {
      float2 T0 = T2[(n2      ) * PAD2 + k1l];
      float2 T1 = T2[(n2 +  64) * PAD2 + k1l];
      float2 Tc = T2[(n2 + 128) * PAD2 + k1l];
      float2 T3 = T2[(n2 + 192) * PAD2 + k1l];
      float sr = fmaf(se, Tc.x, T0.x), si = fmaf(se, Tc.y, T0.y);
      float tr = fmaf(se, T3.x, T1.x), ti = fmaf(se, T3.y, T1.y);
      float ur = ev ? tr : ti;
      float ui = ev ? ti : -tr;
      float yr = fmaf(cc, ur, sr), yi = fmaf(cc, ui, si);
      XAr = fmaf(wAr, yr, fmaf(-wAi, yi, XAr));
      XAi = fmaf(wAr, yi, fmaf( wAi, yr, XAi));
      XBr = fmaf(wBr, yr, fmaf(-wBi, yi, XBr));
      XBi = fmaf(wBr, yi, fmaf( wBi, yr, XBi));
      float nAr = fmaf(wAr, cA, -(wAi * sA));
      float nAi = fmaf(wAr, sA,  (wAi * cA));
      float nBr = fmaf(wBr, cB, -(wBi * sB));
      float nBi = fmaf(wBr, sB,  (wBi * cB));
      wAr = nAr; wAi = nAi; wBr = nBr; wBi = nBi;
    }
    const int k1g = 2 * k1l + half;          // parity-split global k1
    const int mA  = k1g * MM + k2A;
    const int mB  = k1g * MM + k2B;
    ((float2*)Mo)[mA] = make_float2(XAr, XAi);
    ((float2*)Mo)[mB] = make_float2(XBr, XBi);
    if (!isGt) {
      float eA = fmaf(XAr, XAr, XAi * XAi);
      float eB = fmaf(XBr, XBr, XBi * XBi);
      out_energy[(size_t)img * (MM * MM) + mA] = eA;
      out_energy[(size_t)img * (MM * MM) + mB] = eB;
      eacc += eA + eB;
    }
  }

  if (!isGt) {   // block-uniform branch: per-half partial energy
#pragma unroll
    for (int off = 32; off >= 1; off >>= 1) eacc += __shfl_down(eacc, off);
    if (l == 0) red[w] = eacc;
    __syncthreads();
    if (t == 0) totp[2 * img + half] = (red[0] + red[1]) + (red[2] + red[3]);
  }
}

// ---------------------------------------------------------------------------
// Per-mode MLP + elementwise outputs. One thread per (img, mode).
__global__ __launch_bounds__(256) void mlp_kernel(
    const float* __restrict__ Pm, const float* __restrict__ Gm,
    const float* __restrict__ totp,
    const float* __restrict__ W1, const float* __restrict__ b1,
    const float* __restrict__ W2, const float* __restrict__ b2,
    const float* __restrict__ W3, const float* __restrict__ b3,
    float* __restrict__ out)
{
  int gid = blockIdx.x * 256 + threadIdx.x;   // 0 .. 524287
  int img = gid >> 10;

  float2 pm = *(const float2*)&Pm[2 * (size_t)gid];
  float2 gm = *(const float2*)&Gm[2 * (size_t)gid];

  float er = pm.x - gm.x, ei = pm.y - gm.y;
  float merr   = fmaf(er, er, ei * ei);
  float energy = fmaf(pm.x, pm.x, pm.y * pm.y);
  float tot    = totp[2 * img] + totp[2 * img + 1];
  float frac   = energy / (tot + EPSF);

  float h1[64];
#pragma unroll
  for (int j = 0; j < 64; ++j)
    h1[j] = fmaxf(fmaf(pm.x, W1[j], fmaf(pm.y, W1[64 + j], b1[j])), 0.f);

  float h2[32];
#pragma unroll
  for (int k = 0; k < 32; ++k) h2[k] = b2[k];
#pragma unroll
  for (int j = 0; j < 64; ++j) {
#pragma unroll
    for (int k = 0; k < 32; ++k)
      h2[k] = fmaf(h1[j], W2[j * 32 + k], h2[k]);
  }
  float z = b3[0];
#pragma unroll
  for (int k = 0; k < 32; ++k) z = fmaf(fmaxf(h2[k], 0.f), W3[k], z);

  float u = fmaxf(z, 0.f) + log1pf(expf(-fabsf(z)));

  out[O0 + gid] = energy;
  out[O1 + gid] = u;
  out[O2 + gid] = frac;
  out[O3 + gid] = frac * u;
  out[O6 + gid] = merr;
}

// ---------------------------------------------------------------------------
// Per-mode reductions over the 512-image axis: spectra + Pearson correlation.
__global__ __launch_bounds__(64) void corr_kernel(float* __restrict__ out)
{
  int mode = blockIdx.x;     // 0..1023
  int lane = threadIdx.x;    // 0..63

  double su = 0.0, se = 0.0, sen = 0.0, suu = 0.0, see = 0.0, sue = 0.0;
  for (int i = lane; i < NIMG; i += 64) {
    float u  = out[O1 + (size_t)i * 1024 + mode];
    float e  = out[O6 + (size_t)i * 1024 + mode];
    float en = out[O0 + (size_t)i * 1024 + mode];
    su  += (double)u;  se  += (double)e;  sen += (double)en;
    suu += (double)u * (double)u;
    see += (double)e * (double)e;
    sue += (double)u * (double)e;
  }
#pragma unroll
  for (int off = 32; off >= 1; off >>= 1) {
    su  += __shfl_down(su,  off);
    se  += __shfl_down(se,  off);
    sen += __shfl_down(sen, off);
    suu += __shfl_down(suu, off);
    see += __shfl_down(see, off);
    sue += __shfl_down(sue, off);
  }
  if (lane == 0) {
    const double N = (double)NIMG;
    double num = sue - su * se / N;
    double du  = suu - su * su / N;
    double de  = see - se * se / N;
    double den = sqrt(du * de);
    out[O4 + mode] = (float)(su / N);
    out[O5 + mode] = (float)(sen / N);
    out[O7 + mode] = (float)(num / (den + 1e-8));
  }
}

// ---------------------------------------------------------------------------
extern "C" void kernel_launch(void* const* d_in, const int* in_sizes, int n_in,
                              void* d_out, int out_size, void* d_ws, size_t ws_size,
                              hipStream_t stream)
{
  const float* pred = (const float*)d_in[0];
  const float* gt   = (const float*)d_in[2];
  const float* W1   = (const float*)d_in[3];
  const float* b1   = (const float*)d_in[4];
  const float* W2   = (const float*)d_in[5];
  const float* b2   = (const float*)d_in[6];
  const float* W3   = (const float*)d_in[7];
  const float* b3   = (const float*)d_in[8];

  float* out  = (float*)d_out;
  float* ws   = (float*)d_ws;
  float* Pm   = ws + PM_OFF;
  float* Gm   = ws + GM_OFF;
  float* totp = ws + TOT_OFF;

  hipLaunchKernelGGL(dft_kernel, dim3(2048), dim3(256), 0, stream,
                     pred, gt, Pm, Gm, totp, out + O0);
  hipLaunchKernelGGL(mlp_kernel, dim3(2048), dim3(256), 0, stream,
                     Pm, Gm, totp, W1, b1, W2, b2, W3, b3, out);
  hipLaunchKernelGGL(corr_kernel, dim3(1024), dim3(64), 0, stream, out);
}